// Round 14
// baseline (231.244 us; speedup 1.0000x reference)
//
#include <hip/hip_runtime.h>

#define N_NODES 100000
#define N_EDGES 1200000
#define CH 64
#define NG 256
#define OC 8
#define NBUK 196        // ceil(N_NODES/512)
#define BINCHUNK 4096
#define NBLKA 293       // ceil(N_EDGES/BINCHUNK)
#define NSTRIP 6250     // N_NODES/16 (exact)
#define ZERO_U4 4224    // (65536+1024+1024)/16 : gsum+gcnt+gbase

typedef unsigned short ushort_t;
typedef unsigned int uint_t;
typedef __attribute__((ext_vector_type(8))) short bf16x8;
typedef __attribute__((ext_vector_type(4))) float f32x4;

__device__ __forceinline__ ushort_t f2bf(float f) {  // RNE f32->bf16
  uint_t u = __float_as_uint(f);
  return (ushort_t)((u + 0x7FFFu + ((u >> 16) & 1u)) >> 16);
}
__device__ __forceinline__ float bf2f(ushort_t b) {
  return __uint_as_float(((uint_t)b) << 16);
}

// ---------------- prep: W -> bf16 + zero accumulators (replaces 3 memsets) ----
__global__ void prep_k(const float* __restrict__ W1l, const float* __restrict__ W1r,
                       const float* __restrict__ W2l, const float* __restrict__ W2r,
                       ushort_t* __restrict__ wb, uint4* __restrict__ zr) {
  const int gi = blockIdx.x * blockDim.x + threadIdx.x;
  for (int i = gi; i < ZERO_U4; i += gridDim.x * blockDim.x)
    zr[i] = make_uint4(0, 0, 0, 0);
  if (blockIdx.x == 0) {
    for (int k = threadIdx.x; k < CH * CH; k += 256) {
      wb[k]               = f2bf(W1l[k]);
      wb[k + CH * CH]     = f2bf(W1r[k]);
      wb[k + 2 * CH * CH] = f2bf(W2l[k]);
      wb[k + 3 * CH * CH] = f2bf(W2r[k]);
    }
  }
}

// ---------------- pass A1: per-bucket totals (dst>>9) ----------------
__global__ __launch_bounds__(256) void countA_k(const int* __restrict__ dst,
                                                int* __restrict__ gbase) {
  __shared__ int hist[NBUK];
  for (int i = threadIdx.x; i < NBUK; i += 256) hist[i] = 0;
  __syncthreads();
  const int cs = blockIdx.x * BINCHUNK;
  int ce = cs + BINCHUNK;
  if (ce > N_EDGES) ce = N_EDGES;
  for (int e = cs + threadIdx.x; e < ce; e += 256)
    atomicAdd(&hist[dst[e] >> 9], 1);
  __syncthreads();
  for (int b = threadIdx.x; b < NBUK; b += 256) {
    int c = hist[b];
    if (c) atomicAdd(&gbase[b], c);
  }
}

// ---------------- pass B: exclusive scan -> boff; cursor = boff ----------------
__global__ void scanB_k(const int* __restrict__ gbase, int* __restrict__ boff,
                        int* __restrict__ cursor) {
  __shared__ int s[256];
  int v = (threadIdx.x < NBUK) ? gbase[threadIdx.x] : 0;
  s[threadIdx.x] = v;
  __syncthreads();
  for (int o = 1; o < 256; o <<= 1) {
    int t = (threadIdx.x >= o) ? s[threadIdx.x - o] : 0;
    __syncthreads();
    s[threadIdx.x] += t;
    __syncthreads();
  }
  if (threadIdx.x < NBUK) {
    int ex = s[threadIdx.x] - v;
    boff[threadIdx.x] = ex;
    cursor[threadIdx.x] = ex;
  }
  if (threadIdx.x == NBUK - 1) boff[NBUK] = s[threadIdx.x];
}

// ---------------- pass A2: scatter packed edges into bucket regions ----------------
__global__ __launch_bounds__(256) void scatterA_k(const int* __restrict__ src,
                                                  const int* __restrict__ dst,
                                                  int* __restrict__ cursor,
                                                  int* __restrict__ tmp) {
  __shared__ int hist[NBUK];
  for (int i = threadIdx.x; i < NBUK; i += 256) hist[i] = 0;
  __syncthreads();
  const int cs = blockIdx.x * BINCHUNK;
  int ce = cs + BINCHUNK;
  if (ce > N_EDGES) ce = N_EDGES;
  for (int e = cs + threadIdx.x; e < ce; e += 256)
    atomicAdd(&hist[dst[e] >> 9], 1);
  __syncthreads();
  for (int b = threadIdx.x; b < NBUK; b += 256) {
    int c = hist[b];
    hist[b] = c ? atomicAdd(&cursor[b], c) : 0;
  }
  __syncthreads();
  for (int e = cs + threadIdx.x; e < ce; e += 256) {
    int d = dst[e];
    int slot = atomicAdd(&hist[d >> 9], 1);
    tmp[slot] = (src[e] << 9) | (d & 511);
  }
}

// ---------------- pass C: per-bucket fine CSR (rowptr + col) ----------------
// col stores src*CH (pre-scaled row offset).
__global__ __launch_bounds__(512) void csrC_k(const int* __restrict__ tmp,
                                              const int* __restrict__ boff,
                                              int* __restrict__ rp,
                                              int* __restrict__ col) {
  __shared__ int lh[512];
  __shared__ int s[512];
  const int b = blockIdx.x;
  const int tid = threadIdx.x;
  const int eb = boff[b], ee = boff[b + 1];
  lh[tid] = 0;
  __syncthreads();
  for (int e = eb + tid; e < ee; e += 512) atomicAdd(&lh[tmp[e] & 511], 1);
  __syncthreads();
  int v = lh[tid];
  s[tid] = v;
  __syncthreads();
  for (int o = 1; o < 512; o <<= 1) {
    int t = (tid >= o) ? s[tid - o] : 0;
    __syncthreads();
    s[tid] += t;
    __syncthreads();
  }
  const int base = eb + s[tid] - v;
  const int node = b * 512 + tid;
  if (node < N_NODES) rp[node] = base;
  if (b == 0 && tid == 0) rp[N_NODES] = N_EDGES;
  lh[tid] = base;
  __syncthreads();
  for (int e = eb + tid; e < ee; e += 512) {
    int p = tmp[e];
    int slot = atomicAdd(&lh[p & 511], 1);
    col[slot] = (p >> 9) * CH;
  }
}

// ---------------- MFMA dual transform (layer 1): x(f32) -> xl, xr (bf16) ----
// C/D mapping: col=lane&15, row=(lane>>4)*4+reg  [m89-verified].
__global__ __launch_bounds__(256) void transform_mfma_k(
    const float* __restrict__ in, const ushort_t* __restrict__ Wlb,
    const ushort_t* __restrict__ Wrb, ushort_t* __restrict__ outl,
    ushort_t* __restrict__ outr) {
  const int wid = blockIdx.x * 4 + (threadIdx.x >> 6);
  if (wid >= NSTRIP) return;
  const int lane = threadIdx.x & 63;
  const int row = lane & 15;
  const int kb = lane >> 4;  // k-block 0..3 (8 contiguous k each)

  bf16x8 Bfrag[8][2];
#pragma unroll
  for (int t = 0; t < 8; ++t) {
    const ushort_t* W = (t < 4) ? Wlb : Wrb;
    const int j = (t & 3) * 16 + row;
#pragma unroll
    for (int h = 0; h < 2; ++h)
      Bfrag[t][h] = *(const bf16x8*)(W + j * CH + h * 32 + kb * 8);
  }

  const int n0 = wid * 16;
  bf16x8 Afrag[2];
#pragma unroll
  for (int h = 0; h < 2; ++h) {
    const float* p = in + (size_t)(n0 + row) * CH + h * 32 + kb * 8;
    float4 a0 = *(const float4*)p;
    float4 a1 = *(const float4*)(p + 4);
    bf16x8 a;
    a[0] = (short)f2bf(a0.x); a[1] = (short)f2bf(a0.y);
    a[2] = (short)f2bf(a0.z); a[3] = (short)f2bf(a0.w);
    a[4] = (short)f2bf(a1.x); a[5] = (short)f2bf(a1.y);
    a[6] = (short)f2bf(a1.z); a[7] = (short)f2bf(a1.w);
    Afrag[h] = a;
  }

  f32x4 acc[8];
#pragma unroll
  for (int t = 0; t < 8; ++t) {
    acc[t] = (f32x4){0.f, 0.f, 0.f, 0.f};
    acc[t] = __builtin_amdgcn_mfma_f32_16x16x32_bf16(Afrag[0], Bfrag[t][0],
                                                     acc[t], 0, 0, 0);
    acc[t] = __builtin_amdgcn_mfma_f32_16x16x32_bf16(Afrag[1], Bfrag[t][1],
                                                     acc[t], 0, 0, 0);
  }

  const int orow = (lane >> 4) * 4;
#pragma unroll
  for (int t = 0; t < 4; ++t)
#pragma unroll
    for (int i = 0; i < 4; ++i)
      outl[(size_t)(n0 + orow + i) * CH + t * 16 + row] = f2bf(acc[t][i]);
#pragma unroll
  for (int t = 4; t < 8; ++t)
#pragma unroll
    for (int i = 0; i < 4; ++i)
      outr[(size_t)(n0 + orow + i) * CH + (t - 4) * 16 + row] = f2bf(acc[t][i]);
}

// ---------------- FUSED gather-1 + transform-2 ----------------
// One wave per 16-node strip: gather h1 rows (lane=channel) into a per-wave
// XOR-swizzled LDS tile (16B granule g stored at g^(i&7) -> ds_read_b128
// 2-way max = free [m136]), then dual 64x64 MFMA in-wave -> h2l/h2r.
// h1 never touches global memory.
__global__ __launch_bounds__(256) void gather_t2_k(
    const ushort_t* __restrict__ gl, const ushort_t* __restrict__ gr,
    const float* __restrict__ bl, const int* __restrict__ rowptr,
    const int* __restrict__ col, const ushort_t* __restrict__ W2lb,
    const ushort_t* __restrict__ W2rb, ushort_t* __restrict__ outl,
    ushort_t* __restrict__ outr) {
  __shared__ ushort_t lds[4][16][64];
  const int wv = threadIdx.x >> 6;
  const int lane = threadIdx.x & 63;
  const int strip = blockIdx.x * 4 + wv;
  if (strip >= NSTRIP) return;
  const float biasv = bl[lane];
  const int n0 = strip * 16;
  ushort_t(*L)[64] = lds[wv];
  const int sg = lane >> 3;  // store granule (logical)
  const int sw = lane & 7;   // within-granule elem

  for (int i = 0; i < 16; ++i) {
    const int n = n0 + i;
    const int eb = rowptr[n], ee = rowptr[n + 1];
    float a0 = 0.f, a1 = 0.f, a2 = 0.f, a3 = 0.f;
    float a4 = 0.f, a5 = 0.f, a6 = 0.f, a7 = 0.f;
    int e = eb;
    for (; e + 8 <= ee; e += 8) {
      int c0 = col[e],     c1 = col[e + 1], c2 = col[e + 2], c3 = col[e + 3];
      int c4 = col[e + 4], c5 = col[e + 5], c6 = col[e + 6], c7 = col[e + 7];
      a0 += bf2f(gl[(size_t)c0 + lane]);
      a1 += bf2f(gl[(size_t)c1 + lane]);
      a2 += bf2f(gl[(size_t)c2 + lane]);
      a3 += bf2f(gl[(size_t)c3 + lane]);
      a4 += bf2f(gl[(size_t)c4 + lane]);
      a5 += bf2f(gl[(size_t)c5 + lane]);
      a6 += bf2f(gl[(size_t)c6 + lane]);
      a7 += bf2f(gl[(size_t)c7 + lane]);
    }
    for (; e + 4 <= ee; e += 4) {
      int c0 = col[e], c1 = col[e + 1], c2 = col[e + 2], c3 = col[e + 3];
      a0 += bf2f(gl[(size_t)c0 + lane]);
      a1 += bf2f(gl[(size_t)c1 + lane]);
      a2 += bf2f(gl[(size_t)c2 + lane]);
      a3 += bf2f(gl[(size_t)c3 + lane]);
    }
    for (; e < ee; ++e) a0 += bf2f(gl[(size_t)col[e] + lane]);
    const int deg = ee - eb;
    const float inv = deg > 0 ? 1.f / (float)deg : 1.f;
    const float s = ((a0 + a1) + (a2 + a3)) + ((a4 + a5) + (a6 + a7));
    const ushort_t gv = __builtin_nontemporal_load(&gr[(size_t)n * CH + lane]);
    const float r = fmaxf(fmaf(s, inv, biasv + bf2f(gv)), 0.f);
    L[i][((sg ^ (i & 7)) << 3) | sw] = f2bf(r);  // swizzled h1 store
  }

  // ---- in-wave transform 2 ----
  const int row = lane & 15;
  const int kb = lane >> 4;
  bf16x8 Bfrag[8][2];
#pragma unroll
  for (int t = 0; t < 8; ++t) {
    const ushort_t* W = (t < 4) ? W2lb : W2rb;
    const int j = (t & 3) * 16 + row;
#pragma unroll
    for (int h = 0; h < 2; ++h)
      Bfrag[t][h] = *(const bf16x8*)(W + j * CH + h * 32 + kb * 8);
  }
  bf16x8 Afrag[2];
#pragma unroll
  for (int h = 0; h < 2; ++h) {
    const int pg = (kb + 4 * h) ^ (row & 7);  // physical granule (inv swizzle)
    Afrag[h] = *(const bf16x8*)&L[row][pg << 3];
  }
  f32x4 acc[8];
#pragma unroll
  for (int t = 0; t < 8; ++t) {
    acc[t] = (f32x4){0.f, 0.f, 0.f, 0.f};
    acc[t] = __builtin_amdgcn_mfma_f32_16x16x32_bf16(Afrag[0], Bfrag[t][0],
                                                     acc[t], 0, 0, 0);
    acc[t] = __builtin_amdgcn_mfma_f32_16x16x32_bf16(Afrag[1], Bfrag[t][1],
                                                     acc[t], 0, 0, 0);
  }
  const int orow = (lane >> 4) * 4;
#pragma unroll
  for (int t = 0; t < 4; ++t)
#pragma unroll
    for (int i = 0; i < 4; ++i)
      outl[(size_t)(n0 + orow + i) * CH + t * 16 + row] = f2bf(acc[t][i]);
#pragma unroll
  for (int t = 4; t < 8; ++t)
#pragma unroll
    for (int i = 0; i < 4; ++i)
      outr[(size_t)(n0 + orow + i) * CH + (t - 4) * 16 + row] = f2bf(acc[t][i]);
}

// ---------------- gather-2 + mean + bias + relu + pool ----------------
__global__ __launch_bounds__(256) void gather_pool_k(
    const ushort_t* __restrict__ gl, const ushort_t* __restrict__ gr,
    const float* __restrict__ bl, const int* __restrict__ rowptr,
    const int* __restrict__ col, const int* __restrict__ batch,
    float* __restrict__ gsum, int* __restrict__ gcnt) {
  const int lane = threadIdx.x & 63;
  const float biasv = bl[lane];
  const int wid = blockIdx.x * (blockDim.x >> 6) + (threadIdx.x >> 6);
  const int nw = gridDim.x * (blockDim.x >> 6);
  const int per = (N_NODES + nw - 1) / nw;
  int ns = wid * per;
  int ne = ns + per;
  if (ne > N_NODES) ne = N_NODES;
  if (ns >= ne) return;

  int curg = -1;
  float paccv = 0.f;
  int pcnt = 0;

  for (int n = ns; n < ne; ++n) {
    const int eb = rowptr[n], ee = rowptr[n + 1];
    float a0 = 0.f, a1 = 0.f, a2 = 0.f, a3 = 0.f;
    float a4 = 0.f, a5 = 0.f, a6 = 0.f, a7 = 0.f;
    int i = eb;
    for (; i + 8 <= ee; i += 8) {
      int c0 = col[i],     c1 = col[i + 1], c2 = col[i + 2], c3 = col[i + 3];
      int c4 = col[i + 4], c5 = col[i + 5], c6 = col[i + 6], c7 = col[i + 7];
      a0 += bf2f(gl[(size_t)c0 + lane]);
      a1 += bf2f(gl[(size_t)c1 + lane]);
      a2 += bf2f(gl[(size_t)c2 + lane]);
      a3 += bf2f(gl[(size_t)c3 + lane]);
      a4 += bf2f(gl[(size_t)c4 + lane]);
      a5 += bf2f(gl[(size_t)c5 + lane]);
      a6 += bf2f(gl[(size_t)c6 + lane]);
      a7 += bf2f(gl[(size_t)c7 + lane]);
    }
    for (; i + 4 <= ee; i += 4) {
      int c0 = col[i], c1 = col[i + 1], c2 = col[i + 2], c3 = col[i + 3];
      a0 += bf2f(gl[(size_t)c0 + lane]);
      a1 += bf2f(gl[(size_t)c1 + lane]);
      a2 += bf2f(gl[(size_t)c2 + lane]);
      a3 += bf2f(gl[(size_t)c3 + lane]);
    }
    for (; i < ee; ++i) a0 += bf2f(gl[(size_t)col[i] + lane]);
    const int deg = ee - eb;
    const float inv = deg > 0 ? 1.f / (float)deg : 1.f;
    const float s = ((a0 + a1) + (a2 + a3)) + ((a4 + a5) + (a6 + a7));
    const ushort_t gv = __builtin_nontemporal_load(&gr[(size_t)n * CH + lane]);
    const float r = fmaxf(fmaf(s, inv, biasv + bf2f(gv)), 0.f);
    int g = batch[n];
    if (g != curg) {
      if (curg >= 0) {
        atomicAdd(&gsum[curg * CH + lane], paccv);
        if (lane == 0) atomicAdd(&gcnt[curg], pcnt);
      }
      curg = g;
      paccv = 0.f;
      pcnt = 0;
    }
    paccv += r;
    pcnt++;
  }
  if (curg >= 0) {
    atomicAdd(&gsum[curg * CH + lane], paccv);
    if (lane == 0) atomicAdd(&gcnt[curg], pcnt);
  }
}

// ---------------- final projection ----------------
__global__ void final_k(const float* __restrict__ gsum, const int* __restrict__ gcnt,
                        const float* __restrict__ Wc, const float* __restrict__ bc,
                        float* __restrict__ out) {
  __shared__ float Wcs[OC * CH];
  __shared__ float bcs[OC];
  for (int i = threadIdx.x; i < OC * CH; i += blockDim.x) Wcs[i] = Wc[i];
  if (threadIdx.x < OC) bcs[threadIdx.x] = bc[threadIdx.x];
  __syncthreads();
  int g = threadIdx.x;
  float c = (float)gcnt[g];
  float inv = c > 0.f ? 1.f / c : 1.f;
  float gr[CH];
#pragma unroll
  for (int k = 0; k < CH; ++k) gr[k] = gsum[g * CH + k] * inv;
#pragma unroll
  for (int o = 0; o < OC; ++o) {
    float acc = bcs[o];
#pragma unroll
    for (int k = 0; k < CH; ++k) acc += gr[k] * Wcs[o * CH + k];
    out[g * OC + o] = acc;
  }
}

extern "C" void kernel_launch(void* const* d_in, const int* in_sizes, int n_in,
                              void* d_out, int out_size, void* d_ws, size_t ws_size,
                              hipStream_t stream) {
  const float* x   = (const float*)d_in[0];
  const int*   ei  = (const int*)d_in[1];
  const int*   bat = (const int*)d_in[2];
  const float* W1l = (const float*)d_in[3];
  const float* b1l = (const float*)d_in[4];
  const float* W1r = (const float*)d_in[5];
  const float* W2l = (const float*)d_in[6];
  const float* b2l = (const float*)d_in[7];
  const float* W2r = (const float*)d_in[8];
  const float* Wc  = (const float*)d_in[9];
  const float* bc  = (const float*)d_in[10];
  float* out = (float*)d_out;

  char* ws = (char*)d_ws;
  // bf16 node buffers (12.8MB each): buf1=xl, buf2=xr, buf3=h2l, buf4=h2r
  ushort_t* buf1 = (ushort_t*)(ws + 0);
  ushort_t* buf3 = (ushort_t*)(ws + 12800000);
  ushort_t* buf2 = (ushort_t*)(ws + 25600000);
  ushort_t* buf4 = (ushort_t*)(ws + 38400000);
  int*   tmp     = (int*)(ws + 0);              // aliased w/ buf1; CSR phase only
  int*   rp      = (int*)(ws + 51200000);       //    400,128 B (incl pad)
  int*   col     = (int*)(ws + 51600128);       //  4,800,000 B
  // contiguous zero region: gsum + gcnt + gbase (67,584 B)
  float* gsum    = (float*)(ws + 56400128);     //     65,536 B
  int*   gcnt    = (int*)(ws + 56465664);       //      1,024 B
  int*   gbase   = (int*)(ws + 56466688);       //      1,024 B
  int*   boff    = (int*)(ws + 56467712);       //      1,024 B
  int*   cursor  = (int*)(ws + 56468736);       //      1,024 B
  ushort_t* wbf  = (ushort_t*)(ws + 56469760);  //     32,768 B (4x 64x64 bf16)

  const int* src = ei;
  const int* dst = ei + N_EDGES;

  // ---- prep (W->bf16 + zero gsum/gcnt/gbase) + CSR build ----
  prep_k<<<32, 256, 0, stream>>>(W1l, W1r, W2l, W2r, wbf,
                                 (uint4*)(ws + 56400128));
  countA_k<<<NBLKA, 256, 0, stream>>>(dst, gbase);
  scanB_k<<<1, 256, 0, stream>>>(gbase, boff, cursor);
  scatterA_k<<<NBLKA, 256, 0, stream>>>(src, dst, cursor, tmp);
  csrC_k<<<NBUK, 512, 0, stream>>>(tmp, boff, rp, col);

  // ---- layer 1 transform: x(f32) -> xl(buf1), xr(buf2) ----
  transform_mfma_k<<<(NSTRIP + 3) / 4, 256, 0, stream>>>(
      x, wbf, wbf + CH * CH, buf1, buf2);
  // ---- FUSED gather-1 + transform-2: -> h2l(buf3), h2r(buf4) ----
  gather_t2_k<<<(NSTRIP + 3) / 4, 256, 0, stream>>>(
      buf1, buf2, b1l, rp, col, wbf + 2 * CH * CH, wbf + 3 * CH * CH,
      buf3, buf4);
  // ---- gather-2 + pool ----
  gather_pool_k<<<2048, 256, 0, stream>>>(buf3, buf4, b2l, rp, col,
                                          bat, gsum, gcnt);
  // ---- classify ----
  final_k<<<1, 256, 0, stream>>>(gsum, gcnt, Wc, bc, out);
}

// Round 15
// 217.614 us; speedup vs baseline: 1.0626x; 1.0626x over previous
//
#include <hip/hip_runtime.h>

#define N_NODES 100000
#define N_EDGES 1200000
#define CH 64
#define NG 256
#define OC 8
#define NBUK 196        // ceil(N_NODES/512)
#define BINCHUNK 4096
#define NBLKA 293       // ceil(N_EDGES/BINCHUNK)
#define NSTRIP 6250     // N_NODES/16 (exact)
#define ZERO_U4 4224    // (65536+1024+1024)/16 : gsum+gcnt+gbase

typedef unsigned short ushort_t;
typedef unsigned int uint_t;
typedef __attribute__((ext_vector_type(8))) short bf16x8;
typedef __attribute__((ext_vector_type(4))) float f32x4;

__device__ __forceinline__ ushort_t f2bf(float f) {  // RNE f32->bf16
  uint_t u = __float_as_uint(f);
  return (ushort_t)((u + 0x7FFFu + ((u >> 16) & 1u)) >> 16);
}
__device__ __forceinline__ float bf2f(ushort_t b) {
  return __uint_as_float(((uint_t)b) << 16);
}

// ---------------- prep: W -> bf16 + zero accumulators (replaces 3 memsets) ----
__global__ void prep_k(const float* __restrict__ W1l, const float* __restrict__ W1r,
                       const float* __restrict__ W2l, const float* __restrict__ W2r,
                       ushort_t* __restrict__ wb, uint4* __restrict__ zr) {
  const int gi = blockIdx.x * blockDim.x + threadIdx.x;
  for (int i = gi; i < ZERO_U4; i += gridDim.x * blockDim.x)
    zr[i] = make_uint4(0, 0, 0, 0);
  if (blockIdx.x == 0) {
    for (int k = threadIdx.x; k < CH * CH; k += 256) {
      wb[k]               = f2bf(W1l[k]);
      wb[k + CH * CH]     = f2bf(W1r[k]);
      wb[k + 2 * CH * CH] = f2bf(W2l[k]);
      wb[k + 3 * CH * CH] = f2bf(W2r[k]);
    }
  }
}

// ---------------- pass A1: per-bucket totals (dst>>9) ----------------
__global__ __launch_bounds__(256) void countA_k(const int* __restrict__ dst,
                                                int* __restrict__ gbase) {
  __shared__ int hist[NBUK];
  for (int i = threadIdx.x; i < NBUK; i += 256) hist[i] = 0;
  __syncthreads();
  const int cs = blockIdx.x * BINCHUNK;
  int ce = cs + BINCHUNK;
  if (ce > N_EDGES) ce = N_EDGES;
  for (int e = cs + threadIdx.x; e < ce; e += 256)
    atomicAdd(&hist[dst[e] >> 9], 1);
  __syncthreads();
  for (int b = threadIdx.x; b < NBUK; b += 256) {
    int c = hist[b];
    if (c) atomicAdd(&gbase[b], c);
  }
}

// ---------------- pass B: exclusive scan -> boff; cursor = boff ----------------
__global__ void scanB_k(const int* __restrict__ gbase, int* __restrict__ boff,
                        int* __restrict__ cursor) {
  __shared__ int s[256];
  int v = (threadIdx.x < NBUK) ? gbase[threadIdx.x] : 0;
  s[threadIdx.x] = v;
  __syncthreads();
  for (int o = 1; o < 256; o <<= 1) {
    int t = (threadIdx.x >= o) ? s[threadIdx.x - o] : 0;
    __syncthreads();
    s[threadIdx.x] += t;
    __syncthreads();
  }
  if (threadIdx.x < NBUK) {
    int ex = s[threadIdx.x] - v;
    boff[threadIdx.x] = ex;
    cursor[threadIdx.x] = ex;
  }
  if (threadIdx.x == NBUK - 1) boff[NBUK] = s[threadIdx.x];
}

// ---------------- pass A2: scatter packed edges into bucket regions ----------------
__global__ __launch_bounds__(256) void scatterA_k(const int* __restrict__ src,
                                                  const int* __restrict__ dst,
                                                  int* __restrict__ cursor,
                                                  int* __restrict__ tmp) {
  __shared__ int hist[NBUK];
  for (int i = threadIdx.x; i < NBUK; i += 256) hist[i] = 0;
  __syncthreads();
  const int cs = blockIdx.x * BINCHUNK;
  int ce = cs + BINCHUNK;
  if (ce > N_EDGES) ce = N_EDGES;
  for (int e = cs + threadIdx.x; e < ce; e += 256)
    atomicAdd(&hist[dst[e] >> 9], 1);
  __syncthreads();
  for (int b = threadIdx.x; b < NBUK; b += 256) {
    int c = hist[b];
    hist[b] = c ? atomicAdd(&cursor[b], c) : 0;
  }
  __syncthreads();
  for (int e = cs + threadIdx.x; e < ce; e += 256) {
    int d = dst[e];
    int slot = atomicAdd(&hist[d >> 9], 1);
    tmp[slot] = (src[e] << 9) | (d & 511);
  }
}

// ---------------- pass C: per-bucket fine CSR (rowptr + col) ----------------
// col stores src*CH (pre-scaled row offset).
__global__ __launch_bounds__(512) void csrC_k(const int* __restrict__ tmp,
                                              const int* __restrict__ boff,
                                              int* __restrict__ rp,
                                              int* __restrict__ col) {
  __shared__ int lh[512];
  __shared__ int s[512];
  const int b = blockIdx.x;
  const int tid = threadIdx.x;
  const int eb = boff[b], ee = boff[b + 1];
  lh[tid] = 0;
  __syncthreads();
  for (int e = eb + tid; e < ee; e += 512) atomicAdd(&lh[tmp[e] & 511], 1);
  __syncthreads();
  int v = lh[tid];
  s[tid] = v;
  __syncthreads();
  for (int o = 1; o < 512; o <<= 1) {
    int t = (tid >= o) ? s[tid - o] : 0;
    __syncthreads();
    s[tid] += t;
    __syncthreads();
  }
  const int base = eb + s[tid] - v;
  const int node = b * 512 + tid;
  if (node < N_NODES) rp[node] = base;
  if (b == 0 && tid == 0) rp[N_NODES] = N_EDGES;
  lh[tid] = base;
  __syncthreads();
  for (int e = eb + tid; e < ee; e += 512) {
    int p = tmp[e];
    int slot = atomicAdd(&lh[p & 511], 1);
    col[slot] = (p >> 9) * CH;
  }
}

// ---------------- MFMA dual transform: outl/outr (bf16) = in@Wl^T / in@Wr^T ----
// TIN = float (layer 1) or ushort_t (layer 2).
// C/D mapping: col=lane&15, row=(lane>>4)*4+reg  [m89-verified].
template <typename TIN>
__global__ __launch_bounds__(256) void transform_mfma_k(
    const TIN* __restrict__ in, const ushort_t* __restrict__ Wlb,
    const ushort_t* __restrict__ Wrb, ushort_t* __restrict__ outl,
    ushort_t* __restrict__ outr) {
  const int wid = blockIdx.x * 4 + (threadIdx.x >> 6);
  if (wid >= NSTRIP) return;
  const int lane = threadIdx.x & 63;
  const int row = lane & 15;
  const int kb = lane >> 4;  // k-block 0..3 (8 contiguous k each)

  bf16x8 Bfrag[8][2];
#pragma unroll
  for (int t = 0; t < 8; ++t) {
    const ushort_t* W = (t < 4) ? Wlb : Wrb;
    const int j = (t & 3) * 16 + row;
#pragma unroll
    for (int h = 0; h < 2; ++h)
      Bfrag[t][h] = *(const bf16x8*)(W + j * CH + h * 32 + kb * 8);
  }

  const int n0 = wid * 16;
  bf16x8 Afrag[2];
#pragma unroll
  for (int h = 0; h < 2; ++h) {
    if constexpr (sizeof(TIN) == 4) {
      const float* p = (const float*)in + (size_t)(n0 + row) * CH + h * 32 + kb * 8;
      float4 a0 = *(const float4*)p;
      float4 a1 = *(const float4*)(p + 4);
      bf16x8 a;
      a[0] = (short)f2bf(a0.x); a[1] = (short)f2bf(a0.y);
      a[2] = (short)f2bf(a0.z); a[3] = (short)f2bf(a0.w);
      a[4] = (short)f2bf(a1.x); a[5] = (short)f2bf(a1.y);
      a[6] = (short)f2bf(a1.z); a[7] = (short)f2bf(a1.w);
      Afrag[h] = a;
    } else {
      const ushort_t* p =
          (const ushort_t*)in + (size_t)(n0 + row) * CH + h * 32 + kb * 8;
      Afrag[h] = *(const bf16x8*)p;
    }
  }

  f32x4 acc[8];
#pragma unroll
  for (int t = 0; t < 8; ++t) {
    acc[t] = (f32x4){0.f, 0.f, 0.f, 0.f};
    acc[t] = __builtin_amdgcn_mfma_f32_16x16x32_bf16(Afrag[0], Bfrag[t][0],
                                                     acc[t], 0, 0, 0);
    acc[t] = __builtin_amdgcn_mfma_f32_16x16x32_bf16(Afrag[1], Bfrag[t][1],
                                                     acc[t], 0, 0, 0);
  }

  const int orow = (lane >> 4) * 4;
#pragma unroll
  for (int t = 0; t < 4; ++t)
#pragma unroll
    for (int i = 0; i < 4; ++i)
      outl[(size_t)(n0 + orow + i) * CH + t * 16 + row] = f2bf(acc[t][i]);
#pragma unroll
  for (int t = 4; t < 8; ++t)
#pragma unroll
    for (int i = 0; i < 4; ++i)
      outr[(size_t)(n0 + orow + i) * CH + (t - 4) * 16 + row] = f2bf(acc[t][i]);
}

// ---------------- gather(bf16), node-PAIR interleaved for MLP ----------------
// Two nodes' edge walks issue 4+4 independent load chains together, keeping
// ~8 row-reads outstanding even at deg~12 (single-node 8-chain spends most
// iterations in the drain). gr/outh are non-temporal (stream past L2).
template <int MODE>
__global__ __launch_bounds__(256) void gather_k(
    const ushort_t* __restrict__ gl, const ushort_t* __restrict__ gr,
    const float* __restrict__ bl, const int* __restrict__ rowptr,
    const int* __restrict__ col, ushort_t* __restrict__ outh,
    const int* __restrict__ batch, float* __restrict__ gsum,
    int* __restrict__ gcnt) {
  const int lane = threadIdx.x & 63;
  const float biasv = bl[lane];
  const int wid = blockIdx.x * (blockDim.x >> 6) + (threadIdx.x >> 6);
  const int nw = gridDim.x * (blockDim.x >> 6);
  const int per = (N_NODES + nw - 1) / nw;
  int ns = wid * per;
  int ne = ns + per;
  if (ne > N_NODES) ne = N_NODES;
  if (ns >= ne) return;

  int curg = -1;
  float paccv = 0.f;
  int pcnt = 0;

  auto finalize = [&](int n_, int deg, float s) {
    const float inv = deg > 0 ? 1.f / (float)deg : 1.f;
    const ushort_t gv = __builtin_nontemporal_load(&gr[(size_t)n_ * CH + lane]);
    const float r = fmaxf(fmaf(s, inv, biasv + bf2f(gv)), 0.f);
    if (MODE == 0) {
      __builtin_nontemporal_store(f2bf(r), &outh[(size_t)n_ * CH + lane]);
    } else {
      const int g = batch[n_];
      if (g != curg) {
        if (curg >= 0) {
          atomicAdd(&gsum[curg * CH + lane], paccv);
          if (lane == 0) atomicAdd(&gcnt[curg], pcnt);
        }
        curg = g;
        paccv = 0.f;
        pcnt = 0;
      }
      paccv += r;
      pcnt++;
    }
  };

  int n = ns;
  while (n < ne) {
    const bool two = (n + 1 < ne);
    const int eb0 = rowptr[n], ee0 = rowptr[n + 1];
    const int ee1 = two ? rowptr[n + 2] : 0;
    int i0 = eb0, i1 = two ? ee0 : 0;
    float s00 = 0.f, s01 = 0.f, s02 = 0.f, s03 = 0.f;
    float s10 = 0.f, s11 = 0.f, s12 = 0.f, s13 = 0.f;
    // interleaved steady state: 8 independent row loads in flight
    while (i0 + 4 <= ee0 && i1 + 4 <= ee1) {
      int c00 = col[i0], c01 = col[i0 + 1], c02 = col[i0 + 2], c03 = col[i0 + 3];
      int c10 = col[i1], c11 = col[i1 + 1], c12 = col[i1 + 2], c13 = col[i1 + 3];
      s00 += bf2f(gl[(size_t)c00 + lane]);
      s01 += bf2f(gl[(size_t)c01 + lane]);
      s02 += bf2f(gl[(size_t)c02 + lane]);
      s03 += bf2f(gl[(size_t)c03 + lane]);
      s10 += bf2f(gl[(size_t)c10 + lane]);
      s11 += bf2f(gl[(size_t)c11 + lane]);
      s12 += bf2f(gl[(size_t)c12 + lane]);
      s13 += bf2f(gl[(size_t)c13 + lane]);
      i0 += 4;
      i1 += 4;
    }
    for (; i0 + 4 <= ee0; i0 += 4) {
      int c0 = col[i0], c1 = col[i0 + 1], c2 = col[i0 + 2], c3 = col[i0 + 3];
      s00 += bf2f(gl[(size_t)c0 + lane]);
      s01 += bf2f(gl[(size_t)c1 + lane]);
      s02 += bf2f(gl[(size_t)c2 + lane]);
      s03 += bf2f(gl[(size_t)c3 + lane]);
    }
    for (; i1 + 4 <= ee1; i1 += 4) {
      int c0 = col[i1], c1 = col[i1 + 1], c2 = col[i1 + 2], c3 = col[i1 + 3];
      s10 += bf2f(gl[(size_t)c0 + lane]);
      s11 += bf2f(gl[(size_t)c1 + lane]);
      s12 += bf2f(gl[(size_t)c2 + lane]);
      s13 += bf2f(gl[(size_t)c3 + lane]);
    }
    {
      // overlap the two scalar drains (independent chains)
      int r0 = ee0 - i0, r1 = ee1 - i1;
      int m = r0 < r1 ? r0 : r1;
      for (int k = 0; k < m; ++k) {
        s00 += bf2f(gl[(size_t)col[i0 + k] + lane]);
        s10 += bf2f(gl[(size_t)col[i1 + k] + lane]);
      }
      for (int k = m; k < r0; ++k) s00 += bf2f(gl[(size_t)col[i0 + k] + lane]);
      for (int k = m; k < r1; ++k) s10 += bf2f(gl[(size_t)col[i1 + k] + lane]);
    }
    finalize(n, ee0 - eb0, (s00 + s01) + (s02 + s03));
    if (two) finalize(n + 1, ee1 - ee0, (s10 + s11) + (s12 + s13));
    n += 2;
  }
  if (MODE == 1 && curg >= 0) {
    atomicAdd(&gsum[curg * CH + lane], paccv);
    if (lane == 0) atomicAdd(&gcnt[curg], pcnt);
  }
}

// ---------------- final projection ----------------
__global__ void final_k(const float* __restrict__ gsum, const int* __restrict__ gcnt,
                        const float* __restrict__ Wc, const float* __restrict__ bc,
                        float* __restrict__ out) {
  __shared__ float Wcs[OC * CH];
  __shared__ float bcs[OC];
  for (int i = threadIdx.x; i < OC * CH; i += blockDim.x) Wcs[i] = Wc[i];
  if (threadIdx.x < OC) bcs[threadIdx.x] = bc[threadIdx.x];
  __syncthreads();
  int g = threadIdx.x;
  float c = (float)gcnt[g];
  float inv = c > 0.f ? 1.f / c : 1.f;
  float gr[CH];
#pragma unroll
  for (int k = 0; k < CH; ++k) gr[k] = gsum[g * CH + k] * inv;
#pragma unroll
  for (int o = 0; o < OC; ++o) {
    float acc = bcs[o];
#pragma unroll
    for (int k = 0; k < CH; ++k) acc += gr[k] * Wcs[o * CH + k];
    out[g * OC + o] = acc;
  }
}

extern "C" void kernel_launch(void* const* d_in, const int* in_sizes, int n_in,
                              void* d_out, int out_size, void* d_ws, size_t ws_size,
                              hipStream_t stream) {
  const float* x   = (const float*)d_in[0];
  const int*   ei  = (const int*)d_in[1];
  const int*   bat = (const int*)d_in[2];
  const float* W1l = (const float*)d_in[3];
  const float* b1l = (const float*)d_in[4];
  const float* W1r = (const float*)d_in[5];
  const float* W2l = (const float*)d_in[6];
  const float* b2l = (const float*)d_in[7];
  const float* W2r = (const float*)d_in[8];
  const float* Wc  = (const float*)d_in[9];
  const float* bc  = (const float*)d_in[10];
  float* out = (float*)d_out;

  char* ws = (char*)d_ws;
  // row-major bf16 node buffers (12.8MB each):
  //   buf1: xl -> h2l     buf3: h1     buf2: xr -> h2r
  ushort_t* buf1 = (ushort_t*)(ws + 0);         // 12,800,000 B
  ushort_t* buf3 = (ushort_t*)(ws + 12800000);  // 12,800,000 B
  ushort_t* buf2 = (ushort_t*)(ws + 25600000);  // 12,800,000 B
  int*   tmp     = (int*)(ws + 0);              //  4,800,000 B (aliased w/ buf1; CSR phase only)
  int*   rp      = (int*)(ws + 51200000);       //    400,128 B (incl pad)
  int*   col     = (int*)(ws + 51600128);       //  4,800,000 B
  // contiguous zero region: gsum + gcnt + gbase (67,584 B)
  float* gsum    = (float*)(ws + 56400128);     //     65,536 B
  int*   gcnt    = (int*)(ws + 56465664);       //      1,024 B
  int*   gbase   = (int*)(ws + 56466688);       //      1,024 B
  int*   boff    = (int*)(ws + 56467712);       //      1,024 B
  int*   cursor  = (int*)(ws + 56468736);       //      1,024 B
  ushort_t* wbf  = (ushort_t*)(ws + 56469760);  //     32,768 B (4x 64x64 bf16)

  const int* src = ei;
  const int* dst = ei + N_EDGES;

  // ---- prep (W->bf16 + zero gsum/gcnt/gbase) + CSR build ----
  prep_k<<<32, 256, 0, stream>>>(W1l, W1r, W2l, W2r, wbf,
                                 (uint4*)(ws + 56400128));
  countA_k<<<NBLKA, 256, 0, stream>>>(dst, gbase);
  scanB_k<<<1, 256, 0, stream>>>(gbase, boff, cursor);
  scatterA_k<<<NBLKA, 256, 0, stream>>>(src, dst, cursor, tmp);
  csrC_k<<<NBUK, 512, 0, stream>>>(tmp, boff, rp, col);

  // ---- layer 1: x(f32) -> xl(buf1), xr(buf2); gather -> h1(buf3) ----
  transform_mfma_k<float><<<(NSTRIP + 3) / 4, 256, 0, stream>>>(
      x, wbf, wbf + CH * CH, buf1, buf2);
  gather_k<0><<<4096, 256, 0, stream>>>(buf1, buf2, b1l, rp, col, buf3,
                                        nullptr, nullptr, nullptr);
  // ---- layer 2: h1(buf3) -> h2l(buf1), h2r(buf2); gather+pool ----
  transform_mfma_k<ushort_t><<<(NSTRIP + 3) / 4, 256, 0, stream>>>(
      buf3, wbf + 2 * CH * CH, wbf + 3 * CH * CH, buf1, buf2);
  gather_k<1><<<4096, 256, 0, stream>>>(buf1, buf2, b2l, rp, col, nullptr,
                                        bat, gsum, gcnt);
  // ---- classify ----
  final_k<<<1, 256, 0, stream>>>(gsum, gcnt, Wc, bc, out);
}